// Round 2
// baseline (303.553 us; speedup 1.0000x reference)
//
#include <hip/hip_runtime.h>
#include <math.h>

#define SQ    1024
#define INF   128
#define OUTF  64
#define OHH   256
#define TSTR  66            // floats per table row: 64 dims + denom + pad
#define LOG2E 1.44269504088896f

using bf16x8 = __attribute__((ext_vector_type(8))) __bf16;
using f32x4  = __attribute__((ext_vector_type(4))) float;
using u16x8  = __attribute__((ext_vector_type(8))) unsigned short;

#if __has_builtin(__builtin_amdgcn_exp2f)
#define EXP2F(x) __builtin_amdgcn_exp2f(x)
#else
#define EXP2F(x) __expf((x) * 0.6931471805599453f)
#endif

// ---------------------------------------------------------------------------
// Kernel A: per 64-row tile of flattened (N*S, INF) h:
//   WhM = h @ mean-over-heads(W) via 3-term split bf16 MFMA  -> fp32 rows
//   f' = (h@w_f)*log2e, g' = (h@w_g)*log2e via fp32 dots.
// Batch (bx&31) -> XCD bx%8, matching kB/kD consumers.
// ---------------------------------------------------------------------------
__global__ __launch_bounds__(256) void kA(
    const float* __restrict__ h, const float* __restrict__ W,
    const float* __restrict__ a, float* __restrict__ whm,
    float* __restrict__ fo, float* __restrict__ go)
{
    __shared__ __bf16 wmfH[8192];       // B-frag hi (16 KB)
    __shared__ __bf16 wmfL[8192];       // lo residual (16 KB)
    __shared__ float  wfl[INF], wgl[INF]; // prescaled by LOG2E
    __shared__ float  al[2 * OHH];

    const int t    = threadIdx.x;
    const int lane = t & 63;
    const int w    = t >> 6;
    const int bx   = blockIdx.x;
    const int R0   = ((bx & 31) << 10) + ((bx >> 5) << 6);

    al[t]       = a[t];
    al[t + 256] = a[t + 256];

    // WM in B-frag layout, hi/lo split (RNE)
    for (int g = t; g < 2048; g += 256) {
        const int k  = g >> 4;
        const int n0 = (g & 15) << 2;
        const float* Wp = W + k * OHH + n0;
        float4 w0 = *(const float4*)Wp;
        float4 w1 = *(const float4*)(Wp + 64);
        float4 w2 = *(const float4*)(Wp + 128);
        float4 w3 = *(const float4*)(Wp + 192);
        float wm4[4] = {0.25f * (w0.x + w1.x + w2.x + w3.x),
                        0.25f * (w0.y + w1.y + w2.y + w3.y),
                        0.25f * (w0.z + w1.z + w2.z + w3.z),
                        0.25f * (w0.w + w1.w + w2.w + w3.w)};
        const int c = k >> 5, kq = (k >> 3) & 3, id8 = k & 7, T = n0 >> 4;
        const int lbase = kq * 16 + (n0 & 15);
        #pragma unroll
        for (int j = 0; j < 4; ++j) {
            float  v  = wm4[j];
            __bf16 hb = (__bf16)v;
            const int o = ((c * 4 + T) * 64 + lbase + j) * 8 + id8;
            wmfH[o] = hb;
            wmfL[o] = (__bf16)(v - (float)hb);
        }
    }
    __syncthreads();

    // w_f (t<128) / w_g (t>=128)
    {
        const int row = t & 127;
        const float4* Wr = (const float4*)(W + row * OHH);
        const float4* av = (const float4*)(t < 128 ? al : al + OHH);
        float s = 0.f;
        for (int q = 0; q < OHH / 4; ++q) {
            float4 wv = Wr[q], x = av[q];
            s += wv.x * x.x + wv.y * x.y + wv.z * x.z + wv.w * x.w;
        }
        if (t < 128) wfl[row] = s * LOG2E;
        else         wgl[row] = s * LOG2E;
    }
    __syncthreads();

    const int m  = lane & 15;
    const int kq = lane >> 4;
    const float* hrow = h + (size_t)(R0 + w * 16 + m) * INF + kq * 8;

    f32x4 acc[4] = {};
    float sf = 0.f, sg = 0.f;

    #pragma unroll
    for (int c = 0; c < 4; ++c) {
        float4 v0 = *(const float4*)(hrow + c * 32);
        float4 v1 = *(const float4*)(hrow + c * 32 + 4);
        float hv[8] = {v0.x, v0.y, v0.z, v0.w, v1.x, v1.y, v1.z, v1.w};

        float4 wf0 = *(const float4*)(wfl + c * 32 + kq * 8);
        float4 wf1 = *(const float4*)(wfl + c * 32 + kq * 8 + 4);
        float4 wg0 = *(const float4*)(wgl + c * 32 + kq * 8);
        float4 wg1 = *(const float4*)(wgl + c * 32 + kq * 8 + 4);
        float wfv[8] = {wf0.x, wf0.y, wf0.z, wf0.w, wf1.x, wf1.y, wf1.z, wf1.w};
        float wgv[8] = {wg0.x, wg0.y, wg0.z, wg0.w, wg1.x, wg1.y, wg1.z, wg1.w};

        u16x8  ahu;
        bf16x8 alo;
        #pragma unroll
        for (int i = 0; i < 8; ++i) {
            float v = hv[i];
            sf = fmaf(v, wfv[i], sf);
            sg = fmaf(v, wgv[i], sg);
            unsigned u = __float_as_uint(v);
            ahu[i] = (unsigned short)(u >> 16);
            alo[i] = (__bf16)(v - __uint_as_float(u & 0xFFFF0000u));
        }
        bf16x8 ah = __builtin_bit_cast(bf16x8, ahu);

        #pragma unroll
        for (int T = 0; T < 4; ++T) {
            bf16x8 bh = *(const bf16x8*)&wmfH[((c * 4 + T) * 64 + lane) * 8];
            bf16x8 bl = *(const bf16x8*)&wmfL[((c * 4 + T) * 64 + lane) * 8];
            acc[T] = __builtin_amdgcn_mfma_f32_16x16x32_bf16(ah,  bh, acc[T], 0, 0, 0);
            acc[T] = __builtin_amdgcn_mfma_f32_16x16x32_bf16(alo, bh, acc[T], 0, 0, 0);
            acc[T] = __builtin_amdgcn_mfma_f32_16x16x32_bf16(ah,  bl, acc[T], 0, 0, 0);
        }
    }

    sf += __shfl_xor(sf, 16, 64); sf += __shfl_xor(sf, 32, 64);
    sg += __shfl_xor(sg, 16, 64); sg += __shfl_xor(sg, 32, 64);
    if (lane < 16) {
        fo[R0 + w * 16 + m] = sf;
        go[R0 + w * 16 + m] = sg;
    }

    // epilogue: C/D (row = kq*4+r, col = m) -> plain fp32 rows of WhM
    #pragma unroll
    for (int T = 0; T < 4; ++T) {
        #pragma unroll
        for (int r = 0; r < 4; ++r) {
            whm[(size_t)(R0 + w * 16 + kq * 4 + r) * OUTF + T * 16 + m] = acc[T][r];
        }
    }
}

// ---------------------------------------------------------------------------
// Kernel B: per batch (32 blocks):
//   1. bitonic-sort g' (1024, ulong key = sortable(g')<<32 | idx -> fully
//      deterministic w/ index tie-break)
//   2. build directional weighted tables over sorted order:
//        Pre[r][d] = sum_{t<r}  2^{0.1 g'_(t)} WhM[pi(t)][d]   (r in [0,1024])
//        Suf[r][d] = sum_{t>=r} 2^{g'_(t)}     WhM[pi(t)][d]
//      (65th column = denominator weights with WhM -> 1)
//   16 chunks x 2 dirs = 32 wave-units; 16-deep batched L2 gathers; chunk
//   bases scanned in LDS then fixed up by the owning wave (own-writes RMW).
// ---------------------------------------------------------------------------
__global__ __launch_bounds__(256) void kB(
    const float* __restrict__ whm, const float* __restrict__ gi,
    float* __restrict__ gs_out, float* __restrict__ sufA,
    float* __restrict__ preB)
{
    __shared__ unsigned long long keys[1024];       // 8 KB
    __shared__ unsigned short     piL[1024];        // 2 KB
    __shared__ float              wSuf[1024];       // 4 KB
    __shared__ float              wPre[1024];       // 4 KB
    __shared__ float              totals[2][16][TSTR]; // 8.25 KB

    const int t    = threadIdx.x;
    const int lane = t & 63;
    const int wid  = t >> 6;
    const int n    = blockIdx.x;

    // ---- load + encode sortable keys
    for (int i = t; i < 1024; i += 256) {
        unsigned u   = __float_as_uint(gi[n * SQ + i]);
        unsigned key = (u & 0x80000000u) ? ~u : (u | 0x80000000u);
        keys[i] = ((unsigned long long)key << 32) | (unsigned)i;
    }
    __syncthreads();

    // ---- bitonic sort (ascending)
    for (int k = 2; k <= 1024; k <<= 1) {
        for (int j = k >> 1; j > 0; j >>= 1) {
            for (int i = t; i < 1024; i += 256) {
                int p = i ^ j;
                if (p > i) {
                    unsigned long long av = keys[i], bv = keys[p];
                    bool asc = ((i & k) == 0);
                    if ((av > bv) == asc) { keys[i] = bv; keys[p] = av; }
                }
            }
            __syncthreads();
        }
    }

    // ---- decode: sorted g', permutation, exp weights
    for (int i = t; i < 1024; i += 256) {
        unsigned long long kk = keys[i];
        unsigned key = (unsigned)(kk >> 32);
        unsigned u   = (key & 0x80000000u) ? (key & 0x7fffffffu) : ~key;
        float g = __uint_as_float(u);
        piL[i]  = (unsigned short)(kk & 1023u);
        wSuf[i] = EXP2F(g);
        wPre[i] = EXP2F(0.1f * g);
        gs_out[n * SQ + i] = g;
    }
    __syncthreads();

    const float* wb = whm + (size_t)n * (SQ * OUTF);

    // ---- table build: unit = (dir, chunk); 8 units per wave
    for (int s = 0; s < 8; ++s) {
        const int un  = s * 4 + wid;
        const int dir = un >> 4;
        const int c   = un & 15;
        float acc = 0.f, dacc = 0.f;
        if (dir == 0) {                 // prefix: store BEFORE adding elem
            float* Gp = preB + ((size_t)n * 1025 + (size_t)c * 64) * TSTR;
            for (int q0 = 0; q0 < 64; q0 += 16) {
                float vals[16], wv[16];
                #pragma unroll
                for (int u = 0; u < 16; ++u) {
                    int tt = c * 64 + q0 + u;
                    wv[u]   = wPre[tt];
                    vals[u] = wb[(size_t)piL[tt] * OUTF + lane];
                }
                #pragma unroll
                for (int u = 0; u < 16; ++u) {
                    float* row = Gp + (size_t)(q0 + u) * TSTR;
                    row[lane] = acc;
                    if (lane == 0) row[64] = dacc;
                    acc  = fmaf(wv[u], vals[u], acc);
                    dacc += wv[u];
                }
            }
            totals[0][c][lane] = acc;
            if (lane == 0) totals[0][c][64] = dacc;
        } else {                        // suffix: add elem then store
            float* Gs = sufA + ((size_t)n * 1025 + (size_t)c * 64) * TSTR;
            for (int q0 = 48; q0 >= 0; q0 -= 16) {
                float vals[16], wv[16];
                #pragma unroll
                for (int u = 0; u < 16; ++u) {
                    int tt = c * 64 + q0 + u;
                    wv[u]   = wSuf[tt];
                    vals[u] = wb[(size_t)piL[tt] * OUTF + lane];
                }
                #pragma unroll
                for (int u = 15; u >= 0; --u) {
                    acc  = fmaf(wv[u], vals[u], acc);
                    dacc += wv[u];
                    float* row = Gs + (size_t)(q0 + u) * TSTR;
                    row[lane] = acc;
                    if (lane == 0) row[64] = dacc;
                }
            }
            totals[1][c][lane] = acc;
            if (lane == 0) totals[1][c][64] = dacc;
        }
    }
    __syncthreads();

    // ---- fixup: add scanned chunk bases (same wave owns same unit ->
    //      own-writes RMW, no fence needed) + boundary rows at r = 1024
    for (int s = 0; s < 8; ++s) {
        const int un  = s * 4 + wid;
        const int dir = un >> 4;
        const int c   = un & 15;
        if (dir == 0) {
            float base = 0.f, based = 0.f;
            for (int cc = 0; cc < c; ++cc) {
                base  += totals[0][cc][lane];
                based += totals[0][cc][64];
            }
            float* Gp = preB + ((size_t)n * 1025 + (size_t)c * 64) * TSTR;
            if (c > 0) {
                for (int q0 = 0; q0 < 64; q0 += 16) {
                    float vv[16], vd[16];
                    #pragma unroll
                    for (int u = 0; u < 16; ++u) {
                        float* row = Gp + (size_t)(q0 + u) * TSTR;
                        vv[u] = row[lane];
                        vd[u] = row[64];
                    }
                    #pragma unroll
                    for (int u = 0; u < 16; ++u) {
                        float* row = Gp + (size_t)(q0 + u) * TSTR;
                        row[lane] = vv[u] + base;
                        if (lane == 0) row[64] = vd[u] + based;
                    }
                }
            }
            if (c == 15) {
                float* row = preB + ((size_t)n * 1025 + 1024) * TSTR;
                row[lane] = base + totals[0][15][lane];
                if (lane == 0) row[64] = based + totals[0][15][64];
            }
        } else {
            float base = 0.f, based = 0.f;
            for (int cc = c + 1; cc < 16; ++cc) {
                base  += totals[1][cc][lane];
                based += totals[1][cc][64];
            }
            float* Gs = sufA + ((size_t)n * 1025 + (size_t)c * 64) * TSTR;
            if (c < 15) {
                for (int q0 = 0; q0 < 64; q0 += 16) {
                    float vv[16], vd[16];
                    #pragma unroll
                    for (int u = 0; u < 16; ++u) {
                        float* row = Gs + (size_t)(q0 + u) * TSTR;
                        vv[u] = row[lane];
                        vd[u] = row[64];
                    }
                    #pragma unroll
                    for (int u = 0; u < 16; ++u) {
                        float* row = Gs + (size_t)(q0 + u) * TSTR;
                        row[lane] = vv[u] + base;
                        if (lane == 0) row[64] = vd[u] + based;
                    }
                }
            } else {
                float* row = sufA + ((size_t)n * 1025 + 1024) * TSTR;
                row[lane] = 0.f;
                if (lane == 0) row[64] = 0.f;
            }
        }
    }
}

// ---------------------------------------------------------------------------
// Kernel D: per (batch, 64-row i-tile): binary-search r_i over sorted g',
// combine one Suf row + one Pre row, normalize, ELU, store.
// ---------------------------------------------------------------------------
__global__ __launch_bounds__(256) void kD(
    const float* __restrict__ fi, const float* __restrict__ gs,
    const float* __restrict__ sufA, const float* __restrict__ preB,
    float* __restrict__ out)
{
    __shared__ float gsL[1025];

    const int t    = threadIdx.x;
    const int lane = t & 63;
    const int wid  = t >> 6;
    const int n    = blockIdx.x & 31;       // XCD-pinned w/ producer
    const int i0   = (blockIdx.x >> 5) * 64;

    for (int q = t; q < 1024; q += 256) gsL[q] = gs[n * SQ + q];
    if (t == 0) gsL[1024] = 3.0e38f;
    __syncthreads();

    // lanes 0..15 search for the wave's 16 rows (lanes 16+ redundant copies)
    const float myf = fi[n * SQ + i0 + wid * 16 + (lane & 15)];
    {
        // r = first index with gs[idx] > -f'   (upper bound; stable at conv.)
    }
    const float v = -myf;
    int lo = 0, hi = 1024;
    #pragma unroll
    for (int it = 0; it < 10; ++it) {
        int mid = (lo + hi) >> 1;
        bool gt = gsL[mid] > v;
        hi = gt ? mid : hi;
        lo = gt ? lo : mid + 1;
    }

    const float* SA = sufA + (size_t)n * 1025 * TSTR;
    const float* PB = preB + (size_t)n * 1025 * TSTR;
    const size_t orow0 = (size_t)(n * SQ + i0 + wid * 16);

    #pragma unroll 4
    for (int s = 0; s < 16; ++s) {
        int   r  = __shfl(lo,  s, 64);
        float fv = __shfl(myf, s, 64);
        const float* sa = SA + (size_t)r * TSTR;
        const float* pb = PB + (size_t)r * TSTR;
        float sv = sa[lane], pv = pb[lane];
        float sd = sa[64],  pd = pb[64];
        float eP = EXP2F(fv);
        float eN = EXP2F(0.1f * fv);
        float num = eP * sv + eN * pv;
        float den = eP * sd + eN * pd;
        float o = num / den;
        o = o > 0.f ? o : expm1f(o);
        out[(orow0 + s) * OUTF + lane] = o;
    }
}

extern "C" void kernel_launch(void* const* d_in, const int* in_sizes, int n_in,
                              void* d_out, int out_size, void* d_ws, size_t ws_size,
                              hipStream_t stream) {
    const float* h = (const float*)d_in[0];
    // d_in[1] = adj : unused by the reference computation
    const float* W = (const float*)d_in[2];
    const float* a = (const float*)d_in[3];

    char* ws = (char*)d_ws;
    const size_t MB = 1024 * 1024;
    float* whm  = (float*)(ws);                       // 8 MB   fp32 WhM
    float* fb   = (float*)(ws + 8 * MB);              // 128 KB f'
    float* gb   = (float*)(ws + 8 * MB + 131072);     // 128 KB g'
    float* gsO  = (float*)(ws + 8 * MB + 262144);     // 128 KB sorted g'
    float* sufA = (float*)(ws + 9 * MB);              // 8.26 MB suffix table
    float* preB = (float*)(ws + 18 * MB);             // 8.26 MB prefix table
    float* outp = (float*)d_out;

    hipLaunchKernelGGL(kA, dim3(512), dim3(256), 0, stream, h, W, a, whm, fb, gb);
    hipLaunchKernelGGL(kB, dim3(32),  dim3(256), 0, stream, whm, gb, gsO, sufA, preB);
    hipLaunchKernelGGL(kD, dim3(512), dim3(256), 0, stream, fb, gsO, sufA, preB, outp);
}

// Round 3
// 243.226 us; speedup vs baseline: 1.2480x; 1.2480x over previous
//
#include <hip/hip_runtime.h>
#include <math.h>

#define SQ    1024
#define INF   128
#define OUTF  64
#define OHH   256
#define TSTR  66            // floats per table row: 64 dims + denom + pad
#define LOG2E 1.44269504088896f

using bf16x8 = __attribute__((ext_vector_type(8))) __bf16;
using f32x4  = __attribute__((ext_vector_type(4))) float;
using u16x8  = __attribute__((ext_vector_type(8))) unsigned short;

#if __has_builtin(__builtin_amdgcn_exp2f)
#define EXP2F(x) __builtin_amdgcn_exp2f(x)
#else
#define EXP2F(x) __expf((x) * 0.6931471805599453f)
#endif

// ---------------------------------------------------------------------------
// Kernel A: per 64-row tile of flattened (N*S, INF) h:
//   WhM = h @ mean-over-heads(W) via 3-term split bf16 MFMA  -> fp32 rows
//   f' = (h@w_f)*log2e, g' = (h@w_g)*log2e via fp32 dots.
// Batch (bx&31) -> XCD bx%8, matching kB/kD consumers.
// ---------------------------------------------------------------------------
__global__ __launch_bounds__(256) void kA(
    const float* __restrict__ h, const float* __restrict__ W,
    const float* __restrict__ a, float* __restrict__ whm,
    float* __restrict__ fo, float* __restrict__ go)
{
    __shared__ __bf16 wmfH[8192];       // B-frag hi (16 KB)
    __shared__ __bf16 wmfL[8192];       // lo residual (16 KB)
    __shared__ float  wfl[INF], wgl[INF]; // prescaled by LOG2E
    __shared__ float  al[2 * OHH];

    const int t    = threadIdx.x;
    const int lane = t & 63;
    const int w    = t >> 6;
    const int bx   = blockIdx.x;
    const int R0   = ((bx & 31) << 10) + ((bx >> 5) << 6);

    al[t]       = a[t];
    al[t + 256] = a[t + 256];

    // WM in B-frag layout, hi/lo split (RNE)
    for (int g = t; g < 2048; g += 256) {
        const int k  = g >> 4;
        const int n0 = (g & 15) << 2;
        const float* Wp = W + k * OHH + n0;
        float4 w0 = *(const float4*)Wp;
        float4 w1 = *(const float4*)(Wp + 64);
        float4 w2 = *(const float4*)(Wp + 128);
        float4 w3 = *(const float4*)(Wp + 192);
        float wm4[4] = {0.25f * (w0.x + w1.x + w2.x + w3.x),
                        0.25f * (w0.y + w1.y + w2.y + w3.y),
                        0.25f * (w0.z + w1.z + w2.z + w3.z),
                        0.25f * (w0.w + w1.w + w2.w + w3.w)};
        const int c = k >> 5, kq = (k >> 3) & 3, id8 = k & 7, T = n0 >> 4;
        const int lbase = kq * 16 + (n0 & 15);
        #pragma unroll
        for (int j = 0; j < 4; ++j) {
            float  v  = wm4[j];
            __bf16 hb = (__bf16)v;
            const int o = ((c * 4 + T) * 64 + lbase + j) * 8 + id8;
            wmfH[o] = hb;
            wmfL[o] = (__bf16)(v - (float)hb);
        }
    }
    __syncthreads();

    // w_f (t<128) / w_g (t>=128)
    {
        const int row = t & 127;
        const float4* Wr = (const float4*)(W + row * OHH);
        const float4* av = (const float4*)(t < 128 ? al : al + OHH);
        float s = 0.f;
        for (int q = 0; q < OHH / 4; ++q) {
            float4 wv = Wr[q], x = av[q];
            s += wv.x * x.x + wv.y * x.y + wv.z * x.z + wv.w * x.w;
        }
        if (t < 128) wfl[row] = s * LOG2E;
        else         wgl[row] = s * LOG2E;
    }
    __syncthreads();

    const int m  = lane & 15;
    const int kq = lane >> 4;
    const float* hrow = h + (size_t)(R0 + w * 16 + m) * INF + kq * 8;

    f32x4 acc[4] = {};
    float sf = 0.f, sg = 0.f;

    #pragma unroll
    for (int c = 0; c < 4; ++c) {
        float4 v0 = *(const float4*)(hrow + c * 32);
        float4 v1 = *(const float4*)(hrow + c * 32 + 4);
        float hv[8] = {v0.x, v0.y, v0.z, v0.w, v1.x, v1.y, v1.z, v1.w};

        float4 wf0 = *(const float4*)(wfl + c * 32 + kq * 8);
        float4 wf1 = *(const float4*)(wfl + c * 32 + kq * 8 + 4);
        float4 wg0 = *(const float4*)(wgl + c * 32 + kq * 8);
        float4 wg1 = *(const float4*)(wgl + c * 32 + kq * 8 + 4);
        float wfv[8] = {wf0.x, wf0.y, wf0.z, wf0.w, wf1.x, wf1.y, wf1.z, wf1.w};
        float wgv[8] = {wg0.x, wg0.y, wg0.z, wg0.w, wg1.x, wg1.y, wg1.z, wg1.w};

        u16x8  ahu;
        bf16x8 alo;
        #pragma unroll
        for (int i = 0; i < 8; ++i) {
            float v = hv[i];
            sf = fmaf(v, wfv[i], sf);
            sg = fmaf(v, wgv[i], sg);
            unsigned u = __float_as_uint(v);
            ahu[i] = (unsigned short)(u >> 16);
            alo[i] = (__bf16)(v - __uint_as_float(u & 0xFFFF0000u));
        }
        bf16x8 ah = __builtin_bit_cast(bf16x8, ahu);

        #pragma unroll
        for (int T = 0; T < 4; ++T) {
            bf16x8 bh = *(const bf16x8*)&wmfH[((c * 4 + T) * 64 + lane) * 8];
            bf16x8 bl = *(const bf16x8*)&wmfL[((c * 4 + T) * 64 + lane) * 8];
            acc[T] = __builtin_amdgcn_mfma_f32_16x16x32_bf16(ah,  bh, acc[T], 0, 0, 0);
            acc[T] = __builtin_amdgcn_mfma_f32_16x16x32_bf16(alo, bh, acc[T], 0, 0, 0);
            acc[T] = __builtin_amdgcn_mfma_f32_16x16x32_bf16(ah,  bl, acc[T], 0, 0, 0);
        }
    }

    sf += __shfl_xor(sf, 16, 64); sf += __shfl_xor(sf, 32, 64);
    sg += __shfl_xor(sg, 16, 64); sg += __shfl_xor(sg, 32, 64);
    if (lane < 16) {
        fo[R0 + w * 16 + m] = sf;
        go[R0 + w * 16 + m] = sg;
    }

    #pragma unroll
    for (int T = 0; T < 4; ++T) {
        #pragma unroll
        for (int r = 0; r < 4; ++r) {
            whm[(size_t)(R0 + w * 16 + kq * 4 + r) * OUTF + T * 16 + m] = acc[T][r];
        }
    }
}

// ---------------------------------------------------------------------------
// Kernel B1: per batch (32 blocks x 512 threads):
//   1. bitonic-sort g' (ulong key = sortable(g')<<32 | idx, deterministic)
//   2. decode: sorted g', permutation pi, weights 2^g (suf) / 2^{0.1g} (pre)
//      -> global (consumed by kB3/kD)
//   3. per-chunk weighted totals (2 dirs x 16 chunks = 32 wave-units,
//      all 8 waves busy) -> totG[n][dir][c][TSTR]
// ---------------------------------------------------------------------------
__global__ __launch_bounds__(512) void kB1(
    const float* __restrict__ whm, const float* __restrict__ gi,
    float* __restrict__ gs_out, unsigned short* __restrict__ piG,
    float* __restrict__ wSufG, float* __restrict__ wPreG,
    float* __restrict__ totG)
{
    __shared__ unsigned long long keys[1024];       // 8 KB
    __shared__ unsigned short     piL[1024];        // 2 KB
    __shared__ float              wSuf[1024];       // 4 KB
    __shared__ float              wPre[1024];       // 4 KB

    const int t    = threadIdx.x;       // 0..511
    const int lane = t & 63;
    const int wv   = t >> 6;            // 0..7
    const int n    = blockIdx.x;

    for (int i = t; i < 1024; i += 512) {
        unsigned u   = __float_as_uint(gi[n * SQ + i]);
        unsigned key = (u & 0x80000000u) ? ~u : (u | 0x80000000u);
        keys[i] = ((unsigned long long)key << 32) | (unsigned)i;
    }
    __syncthreads();

    for (int k = 2; k <= 1024; k <<= 1) {
        for (int j = k >> 1; j > 0; j >>= 1) {
            for (int i = t; i < 1024; i += 512) {
                int p = i ^ j;
                if (p > i) {
                    unsigned long long av = keys[i], bv = keys[p];
                    bool asc = ((i & k) == 0);
                    if ((av > bv) == asc) { keys[i] = bv; keys[p] = av; }
                }
            }
            __syncthreads();
        }
    }

    for (int i = t; i < 1024; i += 512) {
        unsigned long long kk = keys[i];
        unsigned key = (unsigned)(kk >> 32);
        unsigned u   = (key & 0x80000000u) ? (key & 0x7fffffffu) : ~key;
        float g  = __uint_as_float(u);
        float ws = EXP2F(g);
        float wp = EXP2F(0.1f * g);
        unsigned short pi = (unsigned short)(kk & 1023u);
        piL[i]  = pi;
        wSuf[i] = ws;
        wPre[i] = wp;
        gs_out[n * SQ + i] = g;
        piG[n * SQ + i]    = pi;
        wSufG[n * SQ + i]  = ws;
        wPreG[n * SQ + i]  = wp;
    }
    __syncthreads();

    // ---- chunk totals: unit = dir*16 + c; 4 units per wave
    const float* wb = whm + (size_t)n * (SQ * OUTF);
    for (int s = 0; s < 4; ++s) {
        const int un  = s * 8 + wv;
        const int dir = un >> 4;
        const int c   = un & 15;
        const float* wsel = dir ? wSuf : wPre;
        float acc = 0.f, dacc = 0.f;
        for (int q0 = 0; q0 < 64; q0 += 16) {
            float vals[16], wvv[16];
            #pragma unroll
            for (int u = 0; u < 16; ++u) {
                int tt = c * 64 + q0 + u;
                wvv[u]  = wsel[tt];
                vals[u] = wb[(size_t)piL[tt] * OUTF + lane];
            }
            #pragma unroll
            for (int u = 0; u < 16; ++u) {
                acc  = fmaf(wvv[u], vals[u], acc);
                dacc += wvv[u];
            }
        }
        float* row = totG + ((size_t)(n * 2 + dir) * 16 + c) * TSTR;
        row[lane] = acc;
        if (lane == 0) row[64] = dacc;
    }
}

// ---------------------------------------------------------------------------
// Kernel B3: 1024 wave-units (256 blocks x 4 waves), one (batch, dir, chunk)
// each: base = scan of chunk totals (L2-hot), then stream the chunk's 64
// gathered rows once, writing FINAL table rows (no fixup pass).
//   Pre[r][d] = sum_{t<r}  2^{0.1 g'_(t)} WhM[pi(t)][d]   (r in [0,1024])
//   Suf[r][d] = sum_{t>=r} 2^{g'_(t)}     WhM[pi(t)][d]
// Block bx = k*32 + n  -> batch n on XCD n%8 (matches kA/kB1/kD).
// ---------------------------------------------------------------------------
__global__ __launch_bounds__(256) void kB3(
    const float* __restrict__ whm, const unsigned short* __restrict__ piG,
    const float* __restrict__ wSufG, const float* __restrict__ wPreG,
    const float* __restrict__ totG,
    float* __restrict__ sufA, float* __restrict__ preB)
{
    __shared__ unsigned short piL[1024];    // 2 KB
    __shared__ float          wS[1024];     // 4 KB
    __shared__ float          wP[1024];     // 4 KB

    const int t    = threadIdx.x;
    const int lane = t & 63;
    const int wid  = t >> 6;
    const int n    = blockIdx.x & 31;
    const int un   = (blockIdx.x >> 5) * 4 + wid;   // 0..31
    const int dir  = un >> 4;
    const int c    = un & 15;

    for (int i = t; i < 1024; i += 256) {
        piL[i] = piG[n * SQ + i];
        wS[i]  = wSufG[n * SQ + i];
        wP[i]  = wPreG[n * SQ + i];
    }
    __syncthreads();

    const float* wb = whm + (size_t)n * (SQ * OUTF);
    const float* T0 = totG + (size_t)(n * 2 + dir) * 16 * TSTR;

    float base = 0.f, based = 0.f;
    if (dir == 0) {
        for (int cc = 0; cc < c; ++cc) {
            base  += T0[cc * TSTR + lane];
            based += T0[cc * TSTR + 64];
        }
        float* Gp = preB + ((size_t)n * 1025 + (size_t)c * 64) * TSTR;
        float acc = base, dacc = based;
        for (int q0 = 0; q0 < 64; q0 += 16) {
            float vals[16], wvv[16];
            #pragma unroll
            for (int u = 0; u < 16; ++u) {
                int tt = c * 64 + q0 + u;
                wvv[u]  = wP[tt];
                vals[u] = wb[(size_t)piL[tt] * OUTF + lane];
            }
            #pragma unroll
            for (int u = 0; u < 16; ++u) {
                float* row = Gp + (size_t)(q0 + u) * TSTR;
                row[lane] = acc;                 // prefix: store BEFORE add
                if (lane == 0) row[64] = dacc;
                acc  = fmaf(wvv[u], vals[u], acc);
                dacc += wvv[u];
            }
        }
        if (c == 15) {                           // boundary row r = 1024
            float* row = preB + ((size_t)n * 1025 + 1024) * TSTR;
            row[lane] = acc;
            if (lane == 0) row[64] = dacc;
        }
    } else {
        for (int cc = c + 1; cc < 16; ++cc) {
            base  += T0[cc * TSTR + lane];
            based += T0[cc * TSTR + 64];
        }
        float* Gs = sufA + ((size_t)n * 1025 + (size_t)c * 64) * TSTR;
        float acc = base, dacc = based;
        for (int q0 = 48; q0 >= 0; q0 -= 16) {
            float vals[16], wvv[16];
            #pragma unroll
            for (int u = 0; u < 16; ++u) {
                int tt = c * 64 + q0 + u;
                wvv[u]  = wS[tt];
                vals[u] = wb[(size_t)piL[tt] * OUTF + lane];
            }
            #pragma unroll
            for (int u = 15; u >= 0; --u) {
                acc  = fmaf(wvv[u], vals[u], acc);   // suffix: add THEN store
                dacc += wvv[u];
                float* row = Gs + (size_t)(q0 + u) * TSTR;
                row[lane] = acc;
                if (lane == 0) row[64] = dacc;
            }
        }
        if (c == 15) {                           // boundary row r = 1024
            float* row = sufA + ((size_t)n * 1025 + 1024) * TSTR;
            row[lane] = 0.f;
            if (lane == 0) row[64] = 0.f;
        }
    }
}

// ---------------------------------------------------------------------------
// Kernel D: per (batch, 64-row i-tile): binary-search r_i over sorted g',
// combine one Suf row + one Pre row, normalize, ELU, store.
// ---------------------------------------------------------------------------
__global__ __launch_bounds__(256) void kD(
    const float* __restrict__ fi, const float* __restrict__ gs,
    const float* __restrict__ sufA, const float* __restrict__ preB,
    float* __restrict__ out)
{
    __shared__ float gsL[1025];

    const int t    = threadIdx.x;
    const int lane = t & 63;
    const int wid  = t >> 6;
    const int n    = blockIdx.x & 31;       // XCD-pinned w/ producer
    const int i0   = (blockIdx.x >> 5) * 64;

    for (int q = t; q < 1024; q += 256) gsL[q] = gs[n * SQ + q];
    if (t == 0) gsL[1024] = 3.0e38f;
    __syncthreads();

    const float myf = fi[n * SQ + i0 + wid * 16 + (lane & 15)];
    const float v = -myf;
    int lo = 0, hi = 1024;
    #pragma unroll
    for (int it = 0; it < 10; ++it) {
        int mid = (lo + hi) >> 1;
        bool gt = gsL[mid] > v;
        hi = gt ? mid : hi;
        lo = gt ? lo : mid + 1;
    }

    const float* SA = sufA + (size_t)n * 1025 * TSTR;
    const float* PB = preB + (size_t)n * 1025 * TSTR;
    const size_t orow0 = (size_t)(n * SQ + i0 + wid * 16);

    #pragma unroll 4
    for (int s = 0; s < 16; ++s) {
        int   r  = __shfl(lo,  s, 64);
        float fv = __shfl(myf, s, 64);
        const float* sa = SA + (size_t)r * TSTR;
        const float* pb = PB + (size_t)r * TSTR;
        float sv = sa[lane], pv = pb[lane];
        float sd = sa[64],  pd = pb[64];
        float eP = EXP2F(fv);
        float eN = EXP2F(0.1f * fv);
        float num = eP * sv + eN * pv;
        float den = eP * sd + eN * pd;
        float o = num / den;
        o = o > 0.f ? o : expm1f(o);
        out[(orow0 + s) * OUTF + lane] = o;
    }
}

extern "C" void kernel_launch(void* const* d_in, const int* in_sizes, int n_in,
                              void* d_out, int out_size, void* d_ws, size_t ws_size,
                              hipStream_t stream) {
    const float* h = (const float*)d_in[0];
    // d_in[1] = adj : unused by the reference computation
    const float* W = (const float*)d_in[2];
    const float* a = (const float*)d_in[3];

    char* ws = (char*)d_ws;
    const size_t MB = 1024 * 1024;
    const size_t KB = 1024;
    float*          whm   = (float*)(ws);                        // 8 MB
    float*          fb    = (float*)(ws + 8 * MB);               // 128 KB
    float*          gb    = (float*)(ws + 8 * MB + 128 * KB);    // 128 KB
    float*          gsO   = (float*)(ws + 8 * MB + 256 * KB);    // 128 KB
    float*          wSufG = (float*)(ws + 8 * MB + 384 * KB);    // 128 KB
    float*          wPreG = (float*)(ws + 8 * MB + 512 * KB);    // 128 KB
    unsigned short* piG   = (unsigned short*)(ws + 8 * MB + 640 * KB); // 64 KB
    float*          totG  = (float*)(ws + 8 * MB + 704 * KB);    // 270 KB
    float*          sufA  = (float*)(ws + 10 * MB);              // 8.26 MB
    float*          preB  = (float*)(ws + 19 * MB);              // 8.26 MB
    float*          outp  = (float*)d_out;

    hipLaunchKernelGGL(kA,  dim3(512), dim3(256), 0, stream, h, W, a, whm, fb, gb);
    hipLaunchKernelGGL(kB1, dim3(32),  dim3(512), 0, stream, whm, gb, gsO, piG, wSufG, wPreG, totG);
    hipLaunchKernelGGL(kB3, dim3(256), dim3(256), 0, stream, whm, piG, wSufG, wPreG, totG, sufA, preB);
    hipLaunchKernelGGL(kD,  dim3(512), dim3(256), 0, stream, fb, gsO, sufA, preB, outp);
}

// Round 4
// 234.991 us; speedup vs baseline: 1.2918x; 1.0350x over previous
//
#include <hip/hip_runtime.h>
#include <math.h>

#define SQ    1024
#define INF   128
#define OUTF  64
#define OHH   256
#define TSTR  66            // floats per table row: 64 dims + denom + pad
#define LOG2E 1.44269504088896f

using bf16x8 = __attribute__((ext_vector_type(8))) __bf16;
using f32x4  = __attribute__((ext_vector_type(4))) float;
using u16x8  = __attribute__((ext_vector_type(8))) unsigned short;

#if __has_builtin(__builtin_amdgcn_exp2f)
#define EXP2F(x) __builtin_amdgcn_exp2f(x)
#else
#define EXP2F(x) __expf((x) * 0.6931471805599453f)
#endif

// ---------------------------------------------------------------------------
// Kernel A: per 64-row tile of flattened (N*S, INF) h:
//   WhM = h @ mean-over-heads(W) via 3-term split bf16 MFMA  -> fp32 rows
//   f' = (h@w_f)*log2e, g' = (h@w_g)*log2e via fp32 dots.
// Batch (bx&31) -> XCD bx%8, matching kB/kD consumers.
// ---------------------------------------------------------------------------
__global__ __launch_bounds__(256) void kA(
    const float* __restrict__ h, const float* __restrict__ W,
    const float* __restrict__ a, float* __restrict__ whm,
    float* __restrict__ fo, float* __restrict__ go)
{
    __shared__ __bf16 wmfH[8192];       // B-frag hi (16 KB)
    __shared__ __bf16 wmfL[8192];       // lo residual (16 KB)
    __shared__ float  wfl[INF], wgl[INF]; // prescaled by LOG2E
    __shared__ float  al[2 * OHH];

    const int t    = threadIdx.x;
    const int lane = t & 63;
    const int w    = t >> 6;
    const int bx   = blockIdx.x;
    const int R0   = ((bx & 31) << 10) + ((bx >> 5) << 6);

    al[t]       = a[t];
    al[t + 256] = a[t + 256];

    // WM in B-frag layout, hi/lo split (RNE)
    for (int g = t; g < 2048; g += 256) {
        const int k  = g >> 4;
        const int n0 = (g & 15) << 2;
        const float* Wp = W + k * OHH + n0;
        float4 w0 = *(const float4*)Wp;
        float4 w1 = *(const float4*)(Wp + 64);
        float4 w2 = *(const float4*)(Wp + 128);
        float4 w3 = *(const float4*)(Wp + 192);
        float wm4[4] = {0.25f * (w0.x + w1.x + w2.x + w3.x),
                        0.25f * (w0.y + w1.y + w2.y + w3.y),
                        0.25f * (w0.z + w1.z + w2.z + w3.z),
                        0.25f * (w0.w + w1.w + w2.w + w3.w)};
        const int c = k >> 5, kq = (k >> 3) & 3, id8 = k & 7, T = n0 >> 4;
        const int lbase = kq * 16 + (n0 & 15);
        #pragma unroll
        for (int j = 0; j < 4; ++j) {
            float  v  = wm4[j];
            __bf16 hb = (__bf16)v;
            const int o = ((c * 4 + T) * 64 + lbase + j) * 8 + id8;
            wmfH[o] = hb;
            wmfL[o] = (__bf16)(v - (float)hb);
        }
    }
    __syncthreads();

    // w_f (t<128) / w_g (t>=128)
    {
        const int row = t & 127;
        const float4* Wr = (const float4*)(W + row * OHH);
        const float4* av = (const float4*)(t < 128 ? al : al + OHH);
        float s = 0.f;
        for (int q = 0; q < OHH / 4; ++q) {
            float4 wv = Wr[q], x = av[q];
            s += wv.x * x.x + wv.y * x.y + wv.z * x.z + wv.w * x.w;
        }
        if (t < 128) wfl[row] = s * LOG2E;
        else         wgl[row] = s * LOG2E;
    }
    __syncthreads();

    const int m  = lane & 15;
    const int kq = lane >> 4;
    const float* hrow = h + (size_t)(R0 + w * 16 + m) * INF + kq * 8;

    f32x4 acc[4] = {};
    float sf = 0.f, sg = 0.f;

    #pragma unroll
    for (int c = 0; c < 4; ++c) {
        float4 v0 = *(const float4*)(hrow + c * 32);
        float4 v1 = *(const float4*)(hrow + c * 32 + 4);
        float hv[8] = {v0.x, v0.y, v0.z, v0.w, v1.x, v1.y, v1.z, v1.w};

        float4 wf0 = *(const float4*)(wfl + c * 32 + kq * 8);
        float4 wf1 = *(const float4*)(wfl + c * 32 + kq * 8 + 4);
        float4 wg0 = *(const float4*)(wgl + c * 32 + kq * 8);
        float4 wg1 = *(const float4*)(wgl + c * 32 + kq * 8 + 4);
        float wfv[8] = {wf0.x, wf0.y, wf0.z, wf0.w, wf1.x, wf1.y, wf1.z, wf1.w};
        float wgv[8] = {wg0.x, wg0.y, wg0.z, wg0.w, wg1.x, wg1.y, wg1.z, wg1.w};

        u16x8  ahu;
        bf16x8 alo;
        #pragma unroll
        for (int i = 0; i < 8; ++i) {
            float v = hv[i];
            sf = fmaf(v, wfv[i], sf);
            sg = fmaf(v, wgv[i], sg);
            unsigned u = __float_as_uint(v);
            ahu[i] = (unsigned short)(u >> 16);
            alo[i] = (__bf16)(v - __uint_as_float(u & 0xFFFF0000u));
        }
        bf16x8 ah = __builtin_bit_cast(bf16x8, ahu);

        #pragma unroll
        for (int T = 0; T < 4; ++T) {
            bf16x8 bh = *(const bf16x8*)&wmfH[((c * 4 + T) * 64 + lane) * 8];
            bf16x8 bl = *(const bf16x8*)&wmfL[((c * 4 + T) * 64 + lane) * 8];
            acc[T] = __builtin_amdgcn_mfma_f32_16x16x32_bf16(ah,  bh, acc[T], 0, 0, 0);
            acc[T] = __builtin_amdgcn_mfma_f32_16x16x32_bf16(alo, bh, acc[T], 0, 0, 0);
            acc[T] = __builtin_amdgcn_mfma_f32_16x16x32_bf16(ah,  bl, acc[T], 0, 0, 0);
        }
    }

    sf += __shfl_xor(sf, 16, 64); sf += __shfl_xor(sf, 32, 64);
    sg += __shfl_xor(sg, 16, 64); sg += __shfl_xor(sg, 32, 64);
    if (lane < 16) {
        fo[R0 + w * 16 + m] = sf;
        go[R0 + w * 16 + m] = sg;
    }

    #pragma unroll
    for (int T = 0; T < 4; ++T) {
        #pragma unroll
        for (int r = 0; r < 4; ++r) {
            whm[(size_t)(R0 + w * 16 + kq * 4 + r) * OUTF + T * 16 + m] = acc[T][r];
        }
    }
}

// ---------------------------------------------------------------------------
// Kernel B1: per batch (32 blocks x 1024 threads), register bitonic sort:
//   thread t owns key_t = sortable(g'_t)<<32 | t (deterministic tie-break).
//   Strides j<64: intra-wave __shfl_xor (no LDS, no barrier) -> 45 passes.
//   Strides j>=64: double-buffered LDS, ONE barrier each -> 10 passes.
//   Then decode (sorted g', pi, weights 2^g / 2^{0.1g}) -> global, and
//   per-chunk weighted totals (2 dirs x 16 chunks over 16 waves).
// ---------------------------------------------------------------------------
__global__ __launch_bounds__(1024) void kB1(
    const float* __restrict__ whm, const float* __restrict__ gi,
    float* __restrict__ gs_out, unsigned short* __restrict__ piG,
    float* __restrict__ wSufG, float* __restrict__ wPreG,
    float* __restrict__ totG)
{
    __shared__ unsigned long long kbuf[2][1024];    // 16 KB (long passes)
    __shared__ unsigned short     piL[1024];        // 2 KB
    __shared__ float              wSuf[1024];       // 4 KB
    __shared__ float              wPre[1024];       // 4 KB

    const int t    = threadIdx.x;       // 0..1023 == element index
    const int lane = t & 63;
    const int wv   = t >> 6;            // 0..15
    const int n    = blockIdx.x;

    // sortable key (monotone uint of float) | index
    unsigned u0  = __float_as_uint(gi[n * SQ + t]);
    unsigned key = (u0 & 0x80000000u) ? ~u0 : (u0 | 0x80000000u);
    unsigned long long K = ((unsigned long long)key << 32) | (unsigned)t;

    int pb = 0;
    for (int k = 2; k <= 1024; k <<= 1) {
        for (int j = k >> 1; j > 0; j >>= 1) {
            unsigned long long P;
            if (j < 64) {
                P = __shfl_xor(K, j, 64);           // partner within wave
            } else {
                kbuf[pb][t] = K;
                __syncthreads();
                P = kbuf[pb][t ^ j];
                pb ^= 1;                            // next long pass: other buf
            }
            const bool up      = ((t & k) == 0);
            const bool low     = ((t & j) == 0);
            const bool takeMin = (up == low);
            unsigned long long mn = (K < P) ? K : P;
            unsigned long long mx = (K < P) ? P : K;
            K = takeMin ? mn : mx;
        }
    }

    // decode: thread t holds sorted element at rank t
    {
        unsigned kk = (unsigned)(K >> 32);
        unsigned uu = (kk & 0x80000000u) ? (kk & 0x7fffffffu) : ~kk;
        float g  = __uint_as_float(uu);
        float ws = EXP2F(g);
        float wp = EXP2F(0.1f * g);
        unsigned short pi = (unsigned short)(K & 1023u);
        piL[t]  = pi;
        wSuf[t] = ws;
        wPre[t] = wp;
        gs_out[n * SQ + t] = g;
        piG[n * SQ + t]    = pi;
        wSufG[n * SQ + t]  = ws;
        wPreG[n * SQ + t]  = wp;
    }
    __syncthreads();

    // chunk totals: unit = dir*16 + c; 32 units over 16 waves (2 each)
    const float* wb = whm + (size_t)n * (SQ * OUTF);
    for (int s = 0; s < 2; ++s) {
        const int un  = s * 16 + wv;
        const int dir = un >> 4;
        const int c   = un & 15;
        const float* wsel = dir ? wSuf : wPre;
        float acc = 0.f, dacc = 0.f;
        for (int q0 = 0; q0 < 64; q0 += 16) {
            float vals[16], wvv[16];
            #pragma unroll
            for (int u = 0; u < 16; ++u) {
                int tt = c * 64 + q0 + u;
                wvv[u]  = wsel[tt];
                vals[u] = wb[(size_t)piL[tt] * OUTF + lane];
            }
            #pragma unroll
            for (int u = 0; u < 16; ++u) {
                acc  = fmaf(wvv[u], vals[u], acc);
                dacc += wvv[u];
            }
        }
        float* row = totG + ((size_t)(n * 2 + dir) * 16 + c) * TSTR;
        row[lane] = acc;
        if (lane == 0) row[64] = dacc;
    }
}

// ---------------------------------------------------------------------------
// Kernel B3: 1024 wave-units (256 blocks x 4 waves), one (batch, dir, chunk)
// each: base = scan of chunk totals (L2-hot), then stream the chunk's 64
// gathered rows once, writing FINAL table rows. Barrier-free: the unit's 64
// (pi, w) scalars live one-per-lane in registers, broadcast via __shfl.
//   Pre[r][d] = sum_{t<r}  2^{0.1 g'_(t)} WhM[pi(t)][d]   (r in [0,1024])
//   Suf[r][d] = sum_{t>=r} 2^{g'_(t)}     WhM[pi(t)][d]
// Block bx = k*32 + n  -> batch n on XCD n%8 (matches kA/kB1/kD).
// ---------------------------------------------------------------------------
__global__ __launch_bounds__(256) void kB3(
    const float* __restrict__ whm, const unsigned short* __restrict__ piG,
    const float* __restrict__ wSufG, const float* __restrict__ wPreG,
    const float* __restrict__ totG,
    float* __restrict__ sufA, float* __restrict__ preB)
{
    const int t    = threadIdx.x;
    const int lane = t & 63;
    const int wid  = t >> 6;
    const int n    = blockIdx.x & 31;
    const int un   = (blockIdx.x >> 5) * 4 + wid;   // 0..31
    const int dir  = un >> 4;
    const int c    = un & 15;

    // this unit's 64 element scalars, one per lane
    const int eidx = n * SQ + c * 64 + lane;
    const int   myPi = piG[eidx];
    const float myW  = dir ? wSufG[eidx] : wPreG[eidx];

    const float* wb = whm + (size_t)n * (SQ * OUTF);
    const float* T0 = totG + (size_t)(n * 2 + dir) * 16 * TSTR;

    float base = 0.f, based = 0.f;
    if (dir == 0) {
        for (int cc = 0; cc < c; ++cc) {
            base  += T0[cc * TSTR + lane];
            based += T0[cc * TSTR + 64];
        }
        float* Gp = preB + ((size_t)n * 1025 + (size_t)c * 64) * TSTR;
        float acc = base, dacc = based;
        for (int q0 = 0; q0 < 64; q0 += 16) {
            float vals[16], wvv[16];
            #pragma unroll
            for (int u = 0; u < 16; ++u) {
                int   idx = __shfl(myPi, q0 + u, 64);
                wvv[u]    = __shfl(myW,  q0 + u, 64);
                vals[u]   = wb[(size_t)idx * OUTF + lane];
            }
            #pragma unroll
            for (int u = 0; u < 16; ++u) {
                float* row = Gp + (size_t)(q0 + u) * TSTR;
                row[lane] = acc;                 // prefix: store BEFORE add
                if (lane == 0) row[64] = dacc;
                acc  = fmaf(wvv[u], vals[u], acc);
                dacc += wvv[u];
            }
        }
        if (c == 15) {                           // boundary row r = 1024
            float* row = preB + ((size_t)n * 1025 + 1024) * TSTR;
            row[lane] = acc;
            if (lane == 0) row[64] = dacc;
        }
    } else {
        for (int cc = c + 1; cc < 16; ++cc) {
            base  += T0[cc * TSTR + lane];
            based += T0[cc * TSTR + 64];
        }
        float* Gs = sufA + ((size_t)n * 1025 + (size_t)c * 64) * TSTR;
        float acc = base, dacc = based;
        for (int q0 = 48; q0 >= 0; q0 -= 16) {
            float vals[16], wvv[16];
            #pragma unroll
            for (int u = 0; u < 16; ++u) {
                int   idx = __shfl(myPi, q0 + u, 64);
                wvv[u]    = __shfl(myW,  q0 + u, 64);
                vals[u]   = wb[(size_t)idx * OUTF + lane];
            }
            #pragma unroll
            for (int u = 15; u >= 0; --u) {
                acc  = fmaf(wvv[u], vals[u], acc);   // suffix: add THEN store
                dacc += wvv[u];
                float* row = Gs + (size_t)(q0 + u) * TSTR;
                row[lane] = acc;
                if (lane == 0) row[64] = dacc;
            }
        }
        if (c == 15) {                           // boundary row r = 1024
            float* row = sufA + ((size_t)n * 1025 + 1024) * TSTR;
            row[lane] = 0.f;
            if (lane == 0) row[64] = 0.f;
        }
    }
}

// ---------------------------------------------------------------------------
// Kernel D: per (batch, 64-row i-tile): binary-search r_i over sorted g',
// combine one Suf row + one Pre row, normalize, ELU, store.
// ---------------------------------------------------------------------------
__global__ __launch_bounds__(256) void kD(
    const float* __restrict__ fi, const float* __restrict__ gs,
    const float* __restrict__ sufA, const float* __restrict__ preB,
    float* __restrict__ out)
{
    __shared__ float gsL[1025];

    const int t    = threadIdx.x;
    const int lane = t & 63;
    const int wid  = t >> 6;
    const int n    = blockIdx.x & 31;       // XCD-pinned w/ producer
    const int i0   = (blockIdx.x >> 5) * 64;

    for (int q = t; q < 1024; q += 256) gsL[q] = gs[n * SQ + q];
    if (t == 0) gsL[1024] = 3.0e38f;
    __syncthreads();

    const float myf = fi[n * SQ + i0 + wid * 16 + (lane & 15)];
    const float v = -myf;
    int lo = 0, hi = 1024;
    #pragma unroll
    for (int it = 0; it < 10; ++it) {
        int mid = (lo + hi) >> 1;
        bool gt = gsL[mid] > v;
        hi = gt ? mid : hi;
        lo = gt ? lo : mid + 1;
    }

    const float* SA = sufA + (size_t)n * 1025 * TSTR;
    const float* PB = preB + (size_t)n * 1025 * TSTR;
    const size_t orow0 = (size_t)(n * SQ + i0 + wid * 16);

    #pragma unroll 4
    for (int s = 0; s < 16; ++s) {
        int   r  = __shfl(lo,  s, 64);
        float fv = __shfl(myf, s, 64);
        const float* sa = SA + (size_t)r * TSTR;
        const float* pb = PB + (size_t)r * TSTR;
        float sv = sa[lane], pv = pb[lane];
        float sd = sa[64],  pd = pb[64];
        float eP = EXP2F(fv);
        float eN = EXP2F(0.1f * fv);
        float num = eP * sv + eN * pv;
        float den = eP * sd + eN * pd;
        float o = num / den;
        o = o > 0.f ? o : expm1f(o);
        out[(orow0 + s) * OUTF + lane] = o;
    }
}

extern "C" void kernel_launch(void* const* d_in, const int* in_sizes, int n_in,
                              void* d_out, int out_size, void* d_ws, size_t ws_size,
                              hipStream_t stream) {
    const float* h = (const float*)d_in[0];
    // d_in[1] = adj : unused by the reference computation
    const float* W = (const float*)d_in[2];
    const float* a = (const float*)d_in[3];

    char* ws = (char*)d_ws;
    const size_t MB = 1024 * 1024;
    const size_t KB = 1024;
    float*          whm   = (float*)(ws);                        // 8 MB
    float*          fb    = (float*)(ws + 8 * MB);               // 128 KB
    float*          gb    = (float*)(ws + 8 * MB + 128 * KB);    // 128 KB
    float*          gsO   = (float*)(ws + 8 * MB + 256 * KB);    // 128 KB
    float*          wSufG = (float*)(ws + 8 * MB + 384 * KB);    // 128 KB
    float*          wPreG = (float*)(ws + 8 * MB + 512 * KB);    // 128 KB
    unsigned short* piG   = (unsigned short*)(ws + 8 * MB + 640 * KB); // 64 KB
    float*          totG  = (float*)(ws + 8 * MB + 704 * KB);    // 270 KB
    float*          sufA  = (float*)(ws + 10 * MB);              // 8.26 MB
    float*          preB  = (float*)(ws + 19 * MB);              // 8.26 MB
    float*          outp  = (float*)d_out;

    hipLaunchKernelGGL(kA,  dim3(512), dim3(256),  0, stream, h, W, a, whm, fb, gb);
    hipLaunchKernelGGL(kB1, dim3(32),  dim3(1024), 0, stream, whm, gb, gsO, piG, wSufG, wPreG, totG);
    hipLaunchKernelGGL(kB3, dim3(256), dim3(256),  0, stream, whm, piG, wSufG, wPreG, totG, sufA, preB);
    hipLaunchKernelGGL(kD,  dim3(512), dim3(256),  0, stream, fb, gsO, sufA, preB, outp);
}

// Round 5
// 227.633 us; speedup vs baseline: 1.3335x; 1.0323x over previous
//
#include <hip/hip_runtime.h>
#include <math.h>

#define SQ    1024
#define INF   128
#define OUTF  64
#define OHH   256
#define TSTR  66            // floats per table row: 64 dims + denom + pad
#define LOG2E 1.44269504088896f

using bf16x8 = __attribute__((ext_vector_type(8))) __bf16;
using f32x4  = __attribute__((ext_vector_type(4))) float;
using u16x8  = __attribute__((ext_vector_type(8))) unsigned short;

#if __has_builtin(__builtin_amdgcn_exp2f)
#define EXP2F(x) __builtin_amdgcn_exp2f(x)
#else
#define EXP2F(x) __expf((x) * 0.6931471805599453f)
#endif

// ---------------------------------------------------------------------------
// Kernel A: per 64-row tile of flattened (N*S, INF) h:
//   WhM = h @ mean-over-heads(W) via 3-term split bf16 MFMA  -> fp32 rows
//   f' = (h@w_f)*log2e, g' = (h@w_g)*log2e via fp32 dots.
// Batch (bx&31) -> XCD bx%8, matching kR/kTB3/kD consumers.
// ---------------------------------------------------------------------------
__global__ __launch_bounds__(256) void kA(
    const float* __restrict__ h, const float* __restrict__ W,
    const float* __restrict__ a, float* __restrict__ whm,
    float* __restrict__ fo, float* __restrict__ go)
{
    __shared__ __bf16 wmfH[8192];       // B-frag hi (16 KB)
    __shared__ __bf16 wmfL[8192];       // lo residual (16 KB)
    __shared__ float  wfl[INF], wgl[INF]; // prescaled by LOG2E
    __shared__ float  al[2 * OHH];

    const int t    = threadIdx.x;
    const int lane = t & 63;
    const int w    = t >> 6;
    const int bx   = blockIdx.x;
    const int R0   = ((bx & 31) << 10) + ((bx >> 5) << 6);

    al[t]       = a[t];
    al[t + 256] = a[t + 256];

    // WM in B-frag layout, hi/lo split (RNE)
    for (int g = t; g < 2048; g += 256) {
        const int k  = g >> 4;
        const int n0 = (g & 15) << 2;
        const float* Wp = W + k * OHH + n0;
        float4 w0 = *(const float4*)Wp;
        float4 w1 = *(const float4*)(Wp + 64);
        float4 w2 = *(const float4*)(Wp + 128);
        float4 w3 = *(const float4*)(Wp + 192);
        float wm4[4] = {0.25f * (w0.x + w1.x + w2.x + w3.x),
                        0.25f * (w0.y + w1.y + w2.y + w3.y),
                        0.25f * (w0.z + w1.z + w2.z + w3.z),
                        0.25f * (w0.w + w1.w + w2.w + w3.w)};
        const int c = k >> 5, kq = (k >> 3) & 3, id8 = k & 7, T = n0 >> 4;
        const int lbase = kq * 16 + (n0 & 15);
        #pragma unroll
        for (int j = 0; j < 4; ++j) {
            float  v  = wm4[j];
            __bf16 hb = (__bf16)v;
            const int o = ((c * 4 + T) * 64 + lbase + j) * 8 + id8;
            wmfH[o] = hb;
            wmfL[o] = (__bf16)(v - (float)hb);
        }
    }
    __syncthreads();

    // w_f (t<128) / w_g (t>=128)
    {
        const int row = t & 127;
        const float4* Wr = (const float4*)(W + row * OHH);
        const float4* av = (const float4*)(t < 128 ? al : al + OHH);
        float s = 0.f;
        for (int q = 0; q < OHH / 4; ++q) {
            float4 wv = Wr[q], x = av[q];
            s += wv.x * x.x + wv.y * x.y + wv.z * x.z + wv.w * x.w;
        }
        if (t < 128) wfl[row] = s * LOG2E;
        else         wgl[row] = s * LOG2E;
    }
    __syncthreads();

    const int m  = lane & 15;
    const int kq = lane >> 4;
    const float* hrow = h + (size_t)(R0 + w * 16 + m) * INF + kq * 8;

    f32x4 acc[4] = {};
    float sf = 0.f, sg = 0.f;

    #pragma unroll
    for (int c = 0; c < 4; ++c) {
        float4 v0 = *(const float4*)(hrow + c * 32);
        float4 v1 = *(const float4*)(hrow + c * 32 + 4);
        float hv[8] = {v0.x, v0.y, v0.z, v0.w, v1.x, v1.y, v1.z, v1.w};

        float4 wf0 = *(const float4*)(wfl + c * 32 + kq * 8);
        float4 wf1 = *(const float4*)(wfl + c * 32 + kq * 8 + 4);
        float4 wg0 = *(const float4*)(wgl + c * 32 + kq * 8);
        float4 wg1 = *(const float4*)(wgl + c * 32 + kq * 8 + 4);
        float wfv[8] = {wf0.x, wf0.y, wf0.z, wf0.w, wf1.x, wf1.y, wf1.z, wf1.w};
        float wgv[8] = {wg0.x, wg0.y, wg0.z, wg0.w, wg1.x, wg1.y, wg1.z, wg1.w};

        u16x8  ahu;
        bf16x8 alo;
        #pragma unroll
        for (int i = 0; i < 8; ++i) {
            float v = hv[i];
            sf = fmaf(v, wfv[i], sf);
            sg = fmaf(v, wgv[i], sg);
            unsigned u = __float_as_uint(v);
            ahu[i] = (unsigned short)(u >> 16);
            alo[i] = (__bf16)(v - __uint_as_float(u & 0xFFFF0000u));
        }
        bf16x8 ah = __builtin_bit_cast(bf16x8, ahu);

        #pragma unroll
        for (int T = 0; T < 4; ++T) {
            bf16x8 bh = *(const bf16x8*)&wmfH[((c * 4 + T) * 64 + lane) * 8];
            bf16x8 bl = *(const bf16x8*)&wmfL[((c * 4 + T) * 64 + lane) * 8];
            acc[T] = __builtin_amdgcn_mfma_f32_16x16x32_bf16(ah,  bh, acc[T], 0, 0, 0);
            acc[T] = __builtin_amdgcn_mfma_f32_16x16x32_bf16(alo, bh, acc[T], 0, 0, 0);
            acc[T] = __builtin_amdgcn_mfma_f32_16x16x32_bf16(ah,  bl, acc[T], 0, 0, 0);
        }
    }

    sf += __shfl_xor(sf, 16, 64); sf += __shfl_xor(sf, 32, 64);
    sg += __shfl_xor(sg, 16, 64); sg += __shfl_xor(sg, 32, 64);
    if (lane < 16) {
        fo[R0 + w * 16 + m] = sf;
        go[R0 + w * 16 + m] = sg;
    }

    #pragma unroll
    for (int T = 0; T < 4; ++T) {
        #pragma unroll
        for (int r = 0; r < 4; ++r) {
            whm[(size_t)(R0 + w * 16 + kq * 4 + r) * OUTF + T * 16 + m] = acc[T][r];
        }
    }
}

// ---------------------------------------------------------------------------
// Kernel R: brute-force exact ranking (replaces bitonic sort).
//   Key K_e = sortable(g'_e)<<32 | e  (unique -> exact permutation, identical
//   to the old sort's). rank_e = #{k : K_k < K_e}. 512 blocks (16/batch),
//   each ranks 64 elements; 4 threads/element scan rotated quarters of the
//   batch's 1024 keys from LDS (rotation -> conflict-free broadcast reads),
//   combine via 2 shfl_xor, scatter gs[rank], pi[rank].
// Block bx = qb*32 + n -> batch n on XCD n%8.
// ---------------------------------------------------------------------------
__global__ __launch_bounds__(256) void kR(
    const float* __restrict__ gi, float* __restrict__ gs_out,
    unsigned short* __restrict__ piG)
{
    __shared__ unsigned long long keys[1024];   // 8 KB

    const int t  = threadIdx.x;
    const int n  = blockIdx.x & 31;
    const int qb = blockIdx.x >> 5;             // 0..15: element block

    for (int i = t; i < 1024; i += 256) {
        unsigned u   = __float_as_uint(gi[n * SQ + i]);
        unsigned key = (u & 0x80000000u) ? ~u : (u | 0x80000000u);
        keys[i] = ((unsigned long long)key << 32) | (unsigned)i;
    }
    __syncthreads();

    const int el = t >> 2;          // 0..63: element within block
    const int qt = t & 3;           // scan quarter
    const int e  = qb * 64 + el;    // original index
    const unsigned long long Ke = keys[e];

    int cnt = 0;
    #pragma unroll 16
    for (int s = 0; s < 256; ++s) {
        // rotate start by qt*4 -> the 4 concurrent uniform addresses land in
        // different bank groups (conflict-free broadcast)
        int idx = qt * 256 + ((s + qt * 4) & 255);
        cnt += (keys[idx] < Ke) ? 1 : 0;
    }
    cnt += __shfl_xor(cnt, 1, 64);
    cnt += __shfl_xor(cnt, 2, 64);

    if (qt == 0) {
        unsigned kk = (unsigned)(Ke >> 32);
        unsigned uu = (kk & 0x80000000u) ? (kk & 0x7fffffffu) : ~kk;
        gs_out[n * SQ + cnt] = __uint_as_float(uu);
        piG[n * SQ + cnt]    = (unsigned short)e;
    }
}

// ---------------------------------------------------------------------------
// Kernel TB3: fused chunk-totals + scan + table emit.
//   Pre[r][d] = sum_{t<r}  2^{0.1 g'_(t)} WhM[pi(t)][d]   (r in [0,1024])
//   Suf[r][d] = sum_{t>=r} 2^{g'_(t)}     WhM[pi(t)][d]
// 256 blocks: bx = k*32 + n, k in [0,8): dir = k&1, quarter qu = k>>1.
// Each block redundantly computes ALL 16 chunk totals for its (batch,dir)
// (4 waves x 4 chunks, LDS), one barrier, then each wave emits chunk
// qu*4+wid with the scanned base. Weights recomputed in-register from
// sorted g' (bit-identical to the old stored arrays).
// ---------------------------------------------------------------------------
__global__ __launch_bounds__(256) void kTB3(
    const float* __restrict__ whm, const unsigned short* __restrict__ piG,
    const float* __restrict__ gs,
    float* __restrict__ sufA, float* __restrict__ preB)
{
    __shared__ float          wsel[1024];   // 4 KB: this dir's weights
    __shared__ unsigned short piL[1024];    // 2 KB
    __shared__ float          tot[16][TSTR]; // 4.2 KB

    const int t    = threadIdx.x;
    const int lane = t & 63;
    const int wid  = t >> 6;
    const int n    = blockIdx.x & 31;
    const int k    = blockIdx.x >> 5;   // 0..7
    const int dir  = k & 1;
    const int qu   = k >> 1;            // 0..3

    for (int i = t; i < 1024; i += 256) {
        float g = gs[n * SQ + i];
        wsel[i] = EXP2F(dir ? g : 0.1f * g);
        piL[i]  = piG[n * SQ + i];
    }
    __syncthreads();

    const float* wb = whm + (size_t)n * (SQ * OUTF);

    // ---- totals: wave wid covers chunks wid*4 .. wid*4+3
    for (int cc = 0; cc < 4; ++cc) {
        const int c = wid * 4 + cc;
        float acc = 0.f, dacc = 0.f;
        for (int q0 = 0; q0 < 64; q0 += 16) {
            float vals[16], wvv[16];
            #pragma unroll
            for (int u = 0; u < 16; ++u) {
                int tt = c * 64 + q0 + u;
                wvv[u]  = wsel[tt];
                vals[u] = wb[(size_t)piL[tt] * OUTF + lane];
            }
            #pragma unroll
            for (int u = 0; u < 16; ++u) {
                acc  = fmaf(wvv[u], vals[u], acc);
                dacc += wvv[u];
            }
        }
        tot[c][lane] = acc;
        if (lane == 0) tot[c][64] = dacc;
    }
    __syncthreads();

    // ---- emit chunk c = qu*4 + wid
    const int c = qu * 4 + wid;
    float base = 0.f, based = 0.f;
    if (dir == 0) {
        for (int cc2 = 0; cc2 < c; ++cc2) {
            base  += tot[cc2][lane];
            based += tot[cc2][64];
        }
        float* Gp = preB + ((size_t)n * 1025 + (size_t)c * 64) * TSTR;
        float acc = base, dacc = based;
        for (int q0 = 0; q0 < 64; q0 += 16) {
            float vals[16], wvv[16];
            #pragma unroll
            for (int u = 0; u < 16; ++u) {
                int tt = c * 64 + q0 + u;
                wvv[u]  = wsel[tt];
                vals[u] = wb[(size_t)piL[tt] * OUTF + lane];
            }
            #pragma unroll
            for (int u = 0; u < 16; ++u) {
                float* row = Gp + (size_t)(q0 + u) * TSTR;
                row[lane] = acc;                 // prefix: store BEFORE add
                if (lane == 0) row[64] = dacc;
                acc  = fmaf(wvv[u], vals[u], acc);
                dacc += wvv[u];
            }
        }
        if (c == 15) {                           // boundary row r = 1024
            float* row = preB + ((size_t)n * 1025 + 1024) * TSTR;
            row[lane] = acc;
            if (lane == 0) row[64] = dacc;
        }
    } else {
        for (int cc2 = c + 1; cc2 < 16; ++cc2) {
            base  += tot[cc2][lane];
            based += tot[cc2][64];
        }
        float* Gs = sufA + ((size_t)n * 1025 + (size_t)c * 64) * TSTR;
        float acc = base, dacc = based;
        for (int q0 = 48; q0 >= 0; q0 -= 16) {
            float vals[16], wvv[16];
            #pragma unroll
            for (int u = 0; u < 16; ++u) {
                int tt = c * 64 + q0 + u;
                wvv[u]  = wsel[tt];
                vals[u] = wb[(size_t)piL[tt] * OUTF + lane];
            }
            #pragma unroll
            for (int u = 15; u >= 0; --u) {
                acc  = fmaf(wvv[u], vals[u], acc);   // suffix: add THEN store
                dacc += wvv[u];
                float* row = Gs + (size_t)(q0 + u) * TSTR;
                row[lane] = acc;
                if (lane == 0) row[64] = dacc;
            }
        }
        if (c == 15) {                           // boundary row r = 1024
            float* row = sufA + ((size_t)n * 1025 + 1024) * TSTR;
            row[lane] = 0.f;
            if (lane == 0) row[64] = 0.f;
        }
    }
}

// ---------------------------------------------------------------------------
// Kernel D: per (batch, 64-row i-tile): binary-search r_i over sorted g',
// combine one Suf row + one Pre row, normalize, ELU, store.
// ---------------------------------------------------------------------------
__global__ __launch_bounds__(256) void kD(
    const float* __restrict__ fi, const float* __restrict__ gs,
    const float* __restrict__ sufA, const float* __restrict__ preB,
    float* __restrict__ out)
{
    __shared__ float gsL[1025];

    const int t    = threadIdx.x;
    const int lane = t & 63;
    const int wid  = t >> 6;
    const int n    = blockIdx.x & 31;       // XCD-pinned w/ producer
    const int i0   = (blockIdx.x >> 5) * 64;

    for (int q = t; q < 1024; q += 256) gsL[q] = gs[n * SQ + q];
    if (t == 0) gsL[1024] = 3.0e38f;
    __syncthreads();

    const float myf = fi[n * SQ + i0 + wid * 16 + (lane & 15)];
    const float v = -myf;
    int lo = 0, hi = 1024;
    #pragma unroll
    for (int it = 0; it < 10; ++it) {
        int mid = (lo + hi) >> 1;
        bool gt = gsL[mid] > v;
        hi = gt ? mid : hi;
        lo = gt ? lo : mid + 1;
    }

    const float* SA = sufA + (size_t)n * 1025 * TSTR;
    const float* PB = preB + (size_t)n * 1025 * TSTR;
    const size_t orow0 = (size_t)(n * SQ + i0 + wid * 16);

    #pragma unroll 4
    for (int s = 0; s < 16; ++s) {
        int   r  = __shfl(lo,  s, 64);
        float fv = __shfl(myf, s, 64);
        const float* sa = SA + (size_t)r * TSTR;
        const float* pb = PB + (size_t)r * TSTR;
        float sv = sa[lane], pv = pb[lane];
        float sd = sa[64],  pd = pb[64];
        float eP = EXP2F(fv);
        float eN = EXP2F(0.1f * fv);
        float num = eP * sv + eN * pv;
        float den = eP * sd + eN * pd;
        float o = num / den;
        o = o > 0.f ? o : expm1f(o);
        out[(orow0 + s) * OUTF + lane] = o;
    }
}

extern "C" void kernel_launch(void* const* d_in, const int* in_sizes, int n_in,
                              void* d_out, int out_size, void* d_ws, size_t ws_size,
                              hipStream_t stream) {
    const float* h = (const float*)d_in[0];
    // d_in[1] = adj : unused by the reference computation
    const float* W = (const float*)d_in[2];
    const float* a = (const float*)d_in[3];

    char* ws = (char*)d_ws;
    const size_t MB = 1024 * 1024;
    const size_t KB = 1024;
    float*          whm  = (float*)(ws);                        // 8 MB
    float*          fb   = (float*)(ws + 8 * MB);               // 128 KB
    float*          gb   = (float*)(ws + 8 * MB + 128 * KB);    // 128 KB
    float*          gsO  = (float*)(ws + 8 * MB + 256 * KB);    // 128 KB
    unsigned short* piG  = (unsigned short*)(ws + 8 * MB + 384 * KB); // 64 KB
    float*          sufA = (float*)(ws + 10 * MB);              // 8.26 MB
    float*          preB = (float*)(ws + 19 * MB);              // 8.26 MB
    float*          outp = (float*)d_out;

    hipLaunchKernelGGL(kA,   dim3(512), dim3(256), 0, stream, h, W, a, whm, fb, gb);
    hipLaunchKernelGGL(kR,   dim3(512), dim3(256), 0, stream, gb, gsO, piG);
    hipLaunchKernelGGL(kTB3, dim3(256), dim3(256), 0, stream, whm, piG, gsO, sufA, preB);
    hipLaunchKernelGGL(kD,   dim3(512), dim3(256), 0, stream, fb, gsO, sufA, preB, outp);
}